// Round 8
// baseline (6852.839 us; speedup 1.0000x reference)
//
#include <hip/hip_runtime.h>
#include <hip/hip_bf16.h>

// Problem constants (from reference)
#define N_NODES 50000
#define N_EDGES 150000
#define NODE_IN 64
#define EDGE_IN 16
#define DD 32          // node feature dim
#define EHID 128       // edge-network hidden
#define STEPS 3

__device__ __forceinline__ float b2f(ushort u) {
    union { unsigned int i; float f; } v; v.i = ((unsigned int)u) << 16; return v.f;
}
// dtype-flexible float-input load: bf==1 -> bf16, bf==0 -> fp32
__device__ __forceinline__ float ldin(const void* p, size_t idx, int bf) {
    return bf ? b2f(((const ushort*)p)[idx]) : ((const float*)p)[idx];
}
// width-flexible index load: is64==1 -> int64 elements, else int32
__device__ __forceinline__ int ldidx(const void* p, size_t idx, int is64) {
    return is64 ? (int)(((const long long*)p)[idx]) : ((const int*)p)[idx];
}

// ---------------------------------------------------------------------------
// detect: flag[0] = float dtype (1=bf16, 0=fp32)   [measured: 0 on this harness]
//         flag[1] = edge_index width (1=int64, 0=int32)  [measured: 0]
__global__ __launch_bounds__(256) void detect(const void* __restrict__ wn,
                                              const void* __restrict__ ei,
                                              int* __restrict__ flag) {
    __shared__ int sbad[256], snz[256];
    const ushort* u = (const ushort*)wn;
    const int* e32 = (const int*)ei;
    int t = threadIdx.x;
    int bad = 0, nz = 0;
    for (int i = t * 2; i < 2048; i += 512) {          // even ushort indices
        int ex = (u[i] >> 7) & 0xFF;
        if (ex < 90 || ex > 127) bad++;
    }
    for (int i = 1 + 2 * t; i < 4096; i += 512) {      // odd int32 indices
        if (e32[i] != 0) nz++;
    }
    sbad[t] = bad; snz[t] = nz;
    __syncthreads();
    for (int k = 128; k > 0; k >>= 1) {
        if (t < k) { sbad[t] += sbad[t + k]; snz[t] += snz[t + k]; }
        __syncthreads();
    }
    if (t == 0) {
        flag[0] = (sbad[0] > 100) ? 0 : 1;   // many bad exponents -> fp32
        flag[1] = (snz[0] < 100) ? 1 : 0;    // odd words ~all zero -> int64
    }
}

// ---------------------------------------------------------------------------
// prep_edge_weights: convert We1/be1/be2/We2 to fp32 workspace buffers.
__global__ __launch_bounds__(256) void prep_edge_weights(const void* __restrict__ We1,
                                                         const void* __restrict__ be1,
                                                         const void* __restrict__ be2,
                                                         const void* __restrict__ We2,
                                                         const int* __restrict__ flag,
                                                         float* __restrict__ we1f,
                                                         float* __restrict__ be1f,
                                                         float* __restrict__ be2f,
                                                         float* __restrict__ we2f) {
    int bf = flag[0];
    int i = blockIdx.x * 256 + threadIdx.x;
    if (i < 2048)                 we1f[i]          = ldin(We1, i, bf);
    else if (i < 2048 + 128)      be1f[i - 2048]   = ldin(be1, i - 2048, bf);
    else if (i < 2048 + 128 + 1024) be2f[i - 2176] = ldin(be2, i - 2176, bf);
    else if (i < 2048 + 128 + 1024 + 131072) we2f[i - 3200] = ldin(We2, i - 3200, bf);
}

// ---------------------------------------------------------------------------
// node_init: h = relu(x @ Wn + bn), fp32 out
__global__ __launch_bounds__(256) void node_init(const void* __restrict__ x,
                                                 const void* __restrict__ Wn,
                                                 const void* __restrict__ bn,
                                                 const int* __restrict__ flag,
                                                 float* __restrict__ h) {
    __shared__ float Wns[NODE_IN * DD];   // 8 KB
    int bf = flag[0];
    int t = threadIdx.x;
    for (int i = t; i < NODE_IN * DD; i += 256) Wns[i] = ldin(Wn, i, bf);
    __syncthreads();
    int gid = blockIdx.x * 256 + t;
    int n = gid >> 5, o = gid & 31;
    const size_t xoff = (size_t)n * NODE_IN;
    float s = ldin(bn, o, bf);
#pragma unroll
    for (int i = 0; i < NODE_IN; ++i) s += ldin(x, xoff + i, bf) * Wns[i * DD + o];
    h[(size_t)n * DD + o] = fmaxf(s, 0.f);   // grid exact: n < N always
}

// ---------------------------------------------------------------------------
// msg_valu — direct transcription of the reference einsum/scatter:
//   g[e]   = relu(ea[e] @ We1 + be1)
//   m[e,o] = sum_k g[k]*(sum_i h_i*We2[k][i*32+o]) + sum_i h_i*be2[i*32+o]
//   agg[dst_e][o] += m[e,o]
// Block = 256 threads = 8 edges x 32 outputs. Grid = E/8 = 18750 exact.
__global__ __launch_bounds__(256) void msg_valu(const void* __restrict__ ea,
                                                const float* __restrict__ we1f,
                                                const float* __restrict__ be1f,
                                                const float* __restrict__ we2f,
                                                const float* __restrict__ be2f,
                                                const void* __restrict__ ei,
                                                const float* __restrict__ h,
                                                const int* __restrict__ flag,
                                                float* __restrict__ agg) {
    __shared__ float gs[8][EHID];   // 4 KB
    int bf = flag[0], is64 = flag[1];
    int t = threadIdx.x;
    int el = t >> 5, o = t & 31;
    int e = blockIdx.x * 8 + el;

    // g for this block's 8 edges: each thread computes 4 k-values of its edge
    {
        float ear[EDGE_IN];
        const size_t eoff = (size_t)e * EDGE_IN;
#pragma unroll
        for (int i = 0; i < EDGE_IN; ++i) ear[i] = ldin(ea, eoff + i, bf);
#pragma unroll
        for (int kk = 0; kk < 4; ++kk) {
            int k = o * 4 + kk;
            float s = be1f[k];
#pragma unroll
            for (int i = 0; i < EDGE_IN; ++i) s += ear[i] * we1f[i * EHID + k];
            gs[el][k] = fmaxf(s, 0.f);
        }
    }
    __syncthreads();

    int src = ldidx(ei, e, is64);
    int dst = ldidx(ei, (size_t)N_EDGES + e, is64);

    float hreg[DD];
    const float* hr = h + (size_t)src * DD;
#pragma unroll
    for (int i = 0; i < DD; ++i) hreg[i] = hr[i];

    float m = 0.f;
    for (int k = 0; k < EHID; ++k) {
        float gk = gs[el][k];
        const float* wrow = we2f + (size_t)k * (DD * DD) + o;
        float s = 0.f;
#pragma unroll
        for (int i = 0; i < DD; ++i) s += hreg[i] * wrow[i * DD];
        m += gk * s;
    }
#pragma unroll
    for (int i = 0; i < DD; ++i) m += hreg[i] * be2f[i * DD + o];

    atomicAdd(agg + (size_t)dst * DD + o, m);
}

// ---------------------------------------------------------------------------
// conv + GRU fused, in-place h update. 8 nodes per 256-thr block.
// OUTPUT IS FP32 (reference output dtype = float32 per harness contract).
__global__ __launch_bounds__(256) void conv_gru(const float* __restrict__ agg,
                                                float* __restrict__ h,
                                                const void* __restrict__ Wroot,
                                                const void* __restrict__ bconv,
                                                const void* __restrict__ Wih,
                                                const void* __restrict__ Whh,
                                                const void* __restrict__ bih,
                                                const void* __restrict__ bhh,
                                                const int* __restrict__ flag,
                                                float* __restrict__ out) {
    __shared__ float Wr[DD * 33];      // Wroot[i][o] at i*33+o
    __shared__ float Wi[3 * DD * 33];  // Wih[j][i]  at j*33+i
    __shared__ float Wh[3 * DD * 33];
    __shared__ float bc[DD], bi[3 * DD], bh[3 * DD];
    __shared__ float hs[8][33], cs[8][33];
    int bf = flag[0];
    int t = threadIdx.x;
    for (int i = t; i < DD * DD; i += 256) Wr[(i >> 5) * 33 + (i & 31)] = ldin(Wroot, i, bf);
    for (int i = t; i < 3 * DD * DD; i += 256) {
        Wi[(i >> 5) * 33 + (i & 31)] = ldin(Wih, i, bf);
        Wh[(i >> 5) * 33 + (i & 31)] = ldin(Whh, i, bf);
    }
    if (t < DD) bc[t] = ldin(bconv, t, bf);
    if (t < 3 * DD) { bi[t] = ldin(bih, t, bf); bh[t] = ldin(bhh, t, bf); }

    int ln = t >> 5, o = t & 31;
    int n = blockIdx.x * 8 + ln;     // grid exact: n < N always
    float hval = h[(size_t)n * DD + o];
    hs[ln][o] = hval;
    __syncthreads();

    // conv = relu(agg + h @ Wroot + bconv)
    float s = bc[o] + agg[(size_t)n * DD + o];
#pragma unroll
    for (int i = 0; i < DD; ++i) s += hs[ln][i] * Wr[i * 33 + o];
    float conv = fmaxf(s, 0.f);
    cs[ln][o] = conv;
    __syncthreads();

    // GRU gates (order r, z, n)
    float gir = bi[o], giz = bi[DD + o], gin = bi[2 * DD + o];
    float ghr = bh[o], ghz = bh[DD + o], ghn = bh[2 * DD + o];
#pragma unroll
    for (int i = 0; i < DD; ++i) {
        float c = cs[ln][i], hv = hs[ln][i];
        gir += c * Wi[o * 33 + i];
        giz += c * Wi[(DD + o) * 33 + i];
        gin += c * Wi[(2 * DD + o) * 33 + i];
        ghr += hv * Wh[o * 33 + i];
        ghz += hv * Wh[(DD + o) * 33 + i];
        ghn += hv * Wh[(2 * DD + o) * 33 + i];
    }
    float r = 1.f / (1.f + expf(-(gir + ghr)));
    float z = 1.f / (1.f + expf(-(giz + ghz)));
    float nn = tanhf(gin + r * ghn);
    float hnew = (1.f - z) * nn + z * hval;
    h[(size_t)n * DD + o] = hnew;
    if (out) out[(size_t)n * DD + o] = hnew;   // fp32 store
}

// ---------------------------------------------------------------------------
extern "C" void kernel_launch(void* const* d_in, const int* in_sizes, int n_in,
                              void* d_out, int out_size, void* d_ws, size_t ws_size,
                              hipStream_t stream) {
    const void* x    = d_in[0];
    const void* ei   = d_in[1];
    const void* ea   = d_in[2];
    const void* Wn   = d_in[3];
    const void* bn   = d_in[4];
    const void* We1  = d_in[5];
    const void* be1  = d_in[6];
    const void* We2  = d_in[7];
    const void* be2  = d_in[8];
    const void* Wroot= d_in[9];
    const void* bconv= d_in[10];
    const void* Wih  = d_in[11];
    const void* Whh  = d_in[12];
    const void* bih  = d_in[13];
    const void* bhh  = d_in[14];
    float* out = (float*)d_out;   // fp32 output (reference returns float32)

    // ---- Workspace layout ----
    char* ws = (char*)d_ws;
    float* h    = (float*)(ws);                    // 6.4 MB
    float* agg  = (float*)(ws + 6400000);          // 6.4 MB
    int*   flag = (int*)  (ws + 12800000);         // 64 B
    float* we1f = (float*)(ws + 12800064);         // 8 KB
    float* be1f = (float*)(ws + 12808256);         // 512 B
    float* be2f = (float*)(ws + 12808768);         // 4 KB
    float* we2f = (float*)(ws + 12812864);         // 512 KB  (end: 13,337,152 B)

    detect<<<1, 256, 0, stream>>>(Wn, ei, flag);
    prep_edge_weights<<<(134272 + 255) / 256, 256, 0, stream>>>(We1, be1, be2, We2, flag,
                                                                we1f, be1f, be2f, we2f);
    node_init<<<(N_NODES * DD) / 256, 256, 0, stream>>>(x, Wn, bn, flag, h);

    for (int step = 0; step < STEPS; ++step) {
        hipMemsetAsync(agg, 0, (size_t)N_NODES * DD * sizeof(float), stream);
        msg_valu<<<N_EDGES / 8, 256, 0, stream>>>(ea, we1f, be1f, we2f, be2f,
                                                  ei, h, flag, agg);
        conv_gru<<<N_NODES / 8, 256, 0, stream>>>(agg, h, Wroot, bconv,
                                                  Wih, Whh, bih, bhh, flag,
                                                  (step == STEPS - 1) ? out : nullptr);
    }
}

// Round 9
// 565.615 us; speedup vs baseline: 12.1157x; 12.1157x over previous
//
#include <hip/hip_runtime.h>
#include <hip/hip_bf16.h>

// Problem constants (from reference)
#define N_NODES 50000
#define N_EDGES 150000
#define NODE_IN 64
#define EDGE_IN 16
#define DD 32          // node feature dim
#define EHID 128       // edge-network hidden
#define STEPS 3

// Device-verified harness dtypes: float inputs fp32, edge_index int32, output fp32.
__device__ __forceinline__ ushort f2b(float f) {
    __hip_bfloat16 b = __float2bfloat16(f);   // RNE
    return *reinterpret_cast<ushort*>(&b);
}

typedef __bf16 bf16x8 __attribute__((ext_vector_type(8)));
typedef float  f32x4  __attribute__((ext_vector_type(4)));

#define LDA  136   // As leading dim (ushorts): 272B rows, 16B-aligned, bank-skewed
#define LDAE 40    // Phase-A tiles leading dim (ushorts): 80B rows
#define HPAD 36    // Hs leading dim (floats): 144B rows

// ---------------------------------------------------------------------------
// prep: we2t[n][k] = bf16(We2[k][n]) (n<1024,k<128);
//       we1t[n][k] = bf16(We1[k][n]) zero-padded k to 32 (n<128).
__global__ __launch_bounds__(256) void prep(const float* __restrict__ we2,
                                            const float* __restrict__ we1,
                                            ushort* __restrict__ we2t,
                                            ushort* __restrict__ we1t) {
    int i = blockIdx.x * 256 + threadIdx.x;
    if (i < 131072) {
        int n = i >> 7, k = i & 127;
        we2t[i] = f2b(we2[k * 1024 + n]);
    } else {
        int i2 = i - 131072;                 // < 4096
        int n = i2 >> 5, k = i2 & 31;
        we1t[i2] = (k < EDGE_IN) ? f2b(we1[k * EHID + n]) : (ushort)0;
    }
}

// ---------------------------------------------------------------------------
// node_init: h = relu(x @ Wn + bn), fp32
__global__ __launch_bounds__(256) void node_init(const float* __restrict__ x,
                                                 const float* __restrict__ Wn,
                                                 const float* __restrict__ bn,
                                                 float* __restrict__ h) {
    __shared__ float Wns[NODE_IN * DD];   // 8 KB
    int t = threadIdx.x;
    for (int i = t; i < NODE_IN * DD; i += 256) Wns[i] = Wn[i];
    __syncthreads();
    int gid = blockIdx.x * 256 + t;
    int n = gid >> 5, o = gid & 31;
    const float* xr = x + (size_t)n * NODE_IN;
    float s = bn[o];
#pragma unroll
    for (int i = 0; i < NODE_IN; ++i) s += xr[i] * Wns[i * DD + o];
    h[(size_t)n * DD + o] = fmaxf(s, 0.f);   // grid exact
}

// ---------------------------------------------------------------------------
// fused_msg: one block = 128 edges. No Wm materialization.
//   Phase A (MFMA): g = relu(ea @ We1 + be1) -> bf16 As[128][128]
//   Main (MFMA):    Wm-tiles = As @ We2T-tile, folded immediately:
//                   m_acc[le][o] += h_src[le][i] * (Wm[le][col]+be2[col]),
//                   col=bn*64+nt*16+lr -> i=2bn+(nt>>1), o=16*(nt&1)+lr
//   Scatter:        agg[dst] += m  (atomics)
// Verified fragment mappings (gfx950 16x16x32):
//   A[m=lane&15][k=(lane>>4)*8+j], B[n=lane&15][k=(lane>>4)*8+j],
//   D[row=(lane>>4)*4+reg][col=lane&15]
__global__ __launch_bounds__(256) void fused_msg(const float* __restrict__ ea,
                                                 const ushort* __restrict__ we1t,
                                                 const float* __restrict__ be1,
                                                 const ushort* __restrict__ we2t,
                                                 const float* __restrict__ be2,
                                                 const int* __restrict__ ei,
                                                 const float* __restrict__ h,
                                                 float* __restrict__ agg) {
    __shared__ __attribute__((aligned(16))) ushort AsHs[128 * LDA];      // 34816 B
    __shared__ __attribute__((aligned(16))) ushort U[128 * LDAE * 2];    // 20480 B
    __shared__ float b1s[EHID];                                          // 512 B
    __shared__ float be2s[DD * DD];                                      // 4096 B
    float*  Hs = (float*)AsHs;          // [128][HPAD] view (reuses As after GEMM-A reads)
    ushort* Ae = U;                     // Phase A: [128][LDAE] edge attrs (bf16, k-pad 32)
    ushort* Bw = U + 128 * LDAE;        // Phase A: [128][LDAE] We1T
    ushort* Bs = U;                     // Main:    [64][LDA] We2T tile

    int t = threadIdx.x;
    if (t < EHID) b1s[t] = be1[t];
    for (int i = t; i < DD * DD; i += 256) be2s[i] = be2[i];

    // ---- Stage Ae (bf16 edge attrs, zero pad) + Bw (We1T bf16) ----
    {
        int el = t >> 1, j = t & 1;      // 2 threads per row
        int e = blockIdx.x * 128 + el;
        ushort tmp[8];
        if (e < N_EDGES) {
            const float* er = ea + (size_t)e * EDGE_IN + j * 8;
#pragma unroll
            for (int i = 0; i < 8; ++i) tmp[i] = f2b(er[i]);
        } else {
#pragma unroll
            for (int i = 0; i < 8; ++i) tmp[i] = 0;
        }
        *(uint4*)(&Ae[el * LDAE + j * 8]) = *(uint4*)tmp;
        uint4 z = make_uint4(0u, 0u, 0u, 0u);
        *(uint4*)(&Ae[el * LDAE + 16 + j * 8]) = z;           // k = 16..31 zero
        *(uint4*)(&Bw[el * LDAE + j * 16])     = *(const uint4*)(we1t + el * 32 + j * 16);
        *(uint4*)(&Bw[el * LDAE + j * 16 + 8]) = *(const uint4*)(we1t + el * 32 + j * 16 + 8);
    }
    __syncthreads();

    int w = t >> 6, l = t & 63;
    int lr = l & 15, lg = l >> 4;

    // ---- Phase A: g via MFMA (M=128, N=128 hidden, K=32 padded) ----
    {
        bf16x8 afe[2];
#pragma unroll
        for (int mi = 0; mi < 2; ++mi)
            afe[mi] = *(const bf16x8*)(&Ae[((w * 2 + mi) * 16 + lr) * LDAE + lg * 8]);
#pragma unroll
        for (int nt = 0; nt < 8; ++nt) {
            bf16x8 bfe = *(const bf16x8*)(&Bw[(nt * 16 + lr) * LDAE + lg * 8]);
            int kh = nt * 16 + lr;
            float bb = b1s[kh];
#pragma unroll
            for (int mi = 0; mi < 2; ++mi) {
                f32x4 acc = (f32x4){0.f, 0.f, 0.f, 0.f};
                acc = __builtin_amdgcn_mfma_f32_16x16x32_bf16(afe[mi], bfe, acc, 0, 0, 0);
#pragma unroll
                for (int r = 0; r < 4; ++r) {
                    int row = (w * 2 + mi) * 16 + lg * 4 + r;
                    AsHs[row * LDA + kh] = f2b(fmaxf(acc[r] + bb, 0.f));
                }
            }
        }
    }
    __syncthreads();   // As complete

    // ---- Hoist main-GEMM A fragments ----
    bf16x8 afrag[2][4];
#pragma unroll
    for (int mi = 0; mi < 2; ++mi)
#pragma unroll
        for (int kt = 0; kt < 4; ++kt)
            afrag[mi][kt] = *(const bf16x8*)(&AsHs[((w * 2 + mi) * 16 + lr) * LDA + kt * 32 + lg * 8]);
    __syncthreads();   // As reads done -> reuse as Hs

    // ---- Gather h[src] rows into Hs ----
    {
        int le = t >> 1, half = t & 1;
        int e = blockIdx.x * 128 + le;
        float4* hd = (float4*)(Hs + le * HPAD + half * 16);
        if (e < N_EDGES) {
            int src = ei[e];
            const float4* hr = (const float4*)(h + (size_t)src * DD + half * 16);
            hd[0] = hr[0]; hd[1] = hr[1]; hd[2] = hr[2]; hd[3] = hr[3];
        } else {
            float4 z = make_float4(0.f, 0.f, 0.f, 0.f);
            hd[0] = z; hd[1] = z; hd[2] = z; hd[3] = z;
        }
    }
    __syncthreads();   // Hs ready (also: Ae/Bw reads all done before Bs overwrites U)

    float m_acc[2][4][2];
#pragma unroll
    for (int mi = 0; mi < 2; ++mi)
#pragma unroll
        for (int r = 0; r < 4; ++r) { m_acc[mi][r][0] = 0.f; m_acc[mi][r][1] = 0.f; }

    // ---- Main loop: 16 column tiles of 64 ----
    for (int bn = 0; bn < 16; ++bn) {
        __syncthreads();                 // previous Bs consumed
#pragma unroll
        for (int it = 0; it < 4; ++it) {
            int c = it * 256 + t;        // 64 rows x 16 chunks of 8 bf16
            int row = c >> 4, col = (c & 15) * 8;
            *(uint4*)(&Bs[row * LDA + col]) =
                *(const uint4*)(we2t + (size_t)(bn * 64 + row) * EHID + col);
        }
        __syncthreads();

        f32x4 acc[2][4];
#pragma unroll
        for (int mi = 0; mi < 2; ++mi)
#pragma unroll
            for (int nt = 0; nt < 4; ++nt) acc[mi][nt] = (f32x4){0.f, 0.f, 0.f, 0.f};

#pragma unroll
        for (int kt = 0; kt < 4; ++kt) {
#pragma unroll
            for (int nt = 0; nt < 4; ++nt) {
                bf16x8 b = *(const bf16x8*)(&Bs[(nt * 16 + lr) * LDA + kt * 32 + lg * 8]);
                acc[0][nt] = __builtin_amdgcn_mfma_f32_16x16x32_bf16(afrag[0][kt], b, acc[0][nt], 0, 0, 0);
                acc[1][nt] = __builtin_amdgcn_mfma_f32_16x16x32_bf16(afrag[1][kt], b, acc[1][nt], 0, 0, 0);
            }
        }

        // Fold Wm tile into message accumulators
#pragma unroll
        for (int mi = 0; mi < 2; ++mi) {
#pragma unroll
            for (int r = 0; r < 4; ++r) {
                int row = (w * 2 + mi) * 16 + lg * 4 + r;
                float2 hv = *(const float2*)(Hs + row * HPAD + bn * 2);  // i = 2bn, 2bn+1
#pragma unroll
                for (int nt = 0; nt < 4; ++nt) {
                    int col = bn * 64 + nt * 16 + lr;
                    float hi = (nt >> 1) ? hv.y : hv.x;
                    m_acc[mi][r][nt & 1] += hi * (acc[mi][nt][r] + be2s[col]);
                }
            }
        }
    }

    // ---- Scatter: agg[dst] += m ----
#pragma unroll
    for (int mi = 0; mi < 2; ++mi) {
#pragma unroll
        for (int r = 0; r < 4; ++r) {
            int le = (w * 2 + mi) * 16 + lg * 4 + r;
            int e = blockIdx.x * 128 + le;
            if (e < N_EDGES) {
                int dst = ei[N_EDGES + e];
                float* ar = agg + (size_t)dst * DD;
                atomicAdd(ar + lr,      m_acc[mi][r][0]);
                atomicAdd(ar + lr + 16, m_acc[mi][r][1]);
            }
        }
    }
}

// ---------------------------------------------------------------------------
// conv + GRU fused, in-place h update. 8 nodes per 256-thr block. fp32 out.
__global__ __launch_bounds__(256) void conv_gru(const float* __restrict__ agg,
                                                float* __restrict__ h,
                                                const float* __restrict__ Wroot,
                                                const float* __restrict__ bconv,
                                                const float* __restrict__ Wih,
                                                const float* __restrict__ Whh,
                                                const float* __restrict__ bih,
                                                const float* __restrict__ bhh,
                                                float* __restrict__ out) {
    __shared__ float Wr[DD * 33];
    __shared__ float Wi[3 * DD * 33];
    __shared__ float Wh[3 * DD * 33];
    __shared__ float bc[DD], bi[3 * DD], bh[3 * DD];
    __shared__ float hs[8][33], cs[8][33];
    int t = threadIdx.x;
    for (int i = t; i < DD * DD; i += 256) Wr[(i >> 5) * 33 + (i & 31)] = Wroot[i];
    for (int i = t; i < 3 * DD * DD; i += 256) {
        Wi[(i >> 5) * 33 + (i & 31)] = Wih[i];
        Wh[(i >> 5) * 33 + (i & 31)] = Whh[i];
    }
    if (t < DD) bc[t] = bconv[t];
    if (t < 3 * DD) { bi[t] = bih[t]; bh[t] = bhh[t]; }

    int ln = t >> 5, o = t & 31;
    int n = blockIdx.x * 8 + ln;     // grid exact
    float hval = h[(size_t)n * DD + o];
    hs[ln][o] = hval;
    __syncthreads();

    float s = bc[o] + agg[(size_t)n * DD + o];
#pragma unroll
    for (int i = 0; i < DD; ++i) s += hs[ln][i] * Wr[i * 33 + o];
    float conv = fmaxf(s, 0.f);
    cs[ln][o] = conv;
    __syncthreads();

    float gir = bi[o], giz = bi[DD + o], gin = bi[2 * DD + o];
    float ghr = bh[o], ghz = bh[DD + o], ghn = bh[2 * DD + o];
#pragma unroll
    for (int i = 0; i < DD; ++i) {
        float c = cs[ln][i], hv = hs[ln][i];
        gir += c * Wi[o * 33 + i];
        giz += c * Wi[(DD + o) * 33 + i];
        gin += c * Wi[(2 * DD + o) * 33 + i];
        ghr += hv * Wh[o * 33 + i];
        ghz += hv * Wh[(DD + o) * 33 + i];
        ghn += hv * Wh[(2 * DD + o) * 33 + i];
    }
    float r = 1.f / (1.f + expf(-(gir + ghr)));
    float z = 1.f / (1.f + expf(-(giz + ghz)));
    float nn = tanhf(gin + r * ghn);
    float hnew = (1.f - z) * nn + z * hval;
    h[(size_t)n * DD + o] = hnew;
    if (out) out[(size_t)n * DD + o] = hnew;
}

// ---------------------------------------------------------------------------
extern "C" void kernel_launch(void* const* d_in, const int* in_sizes, int n_in,
                              void* d_out, int out_size, void* d_ws, size_t ws_size,
                              hipStream_t stream) {
    const float* x    = (const float*)d_in[0];
    const int*   ei   = (const int*)d_in[1];
    const float* ea   = (const float*)d_in[2];
    const float* Wn   = (const float*)d_in[3];
    const float* bn   = (const float*)d_in[4];
    const float* We1  = (const float*)d_in[5];
    const float* be1  = (const float*)d_in[6];
    const float* We2  = (const float*)d_in[7];
    const float* be2  = (const float*)d_in[8];
    const float* Wroot= (const float*)d_in[9];
    const float* bconv= (const float*)d_in[10];
    const float* Wih  = (const float*)d_in[11];
    const float* Whh  = (const float*)d_in[12];
    const float* bih  = (const float*)d_in[13];
    const float* bhh  = (const float*)d_in[14];
    float* out = (float*)d_out;   // fp32 output (device-verified)

    // ---- Workspace: 13.07 MB (within proven-safe bound) ----
    char* ws = (char*)d_ws;
    float*  h    = (float*)(ws);                    // 6.4 MB
    float*  agg  = (float*)(ws + 6400000);          // 6.4 MB
    ushort* we2t = (ushort*)(ws + 12800000);        // 256 KB [1024][128] bf16
    ushort* we1t = (ushort*)(ws + 13062144);        // 8 KB   [128][32]  bf16

    prep<<<528, 256, 0, stream>>>(We2, We1, we2t, we1t);
    node_init<<<(N_NODES * DD) / 256, 256, 0, stream>>>(x, Wn, bn, h);

    for (int step = 0; step < STEPS; ++step) {
        hipMemsetAsync(agg, 0, (size_t)N_NODES * DD * sizeof(float), stream);
        fused_msg<<<(N_EDGES + 127) / 128, 256, 0, stream>>>(ea, we1t, be1, we2t, be2,
                                                             ei, h, agg);
        conv_gru<<<N_NODES / 8, 256, 0, stream>>>(agg, h, Wroot, bconv,
                                                  Wih, Whh, bih, bhh,
                                                  (step == STEPS - 1) ? out : nullptr);
    }
}

// Round 10
// 466.921 us; speedup vs baseline: 14.6767x; 1.2114x over previous
//
#include <hip/hip_runtime.h>
#include <hip/hip_bf16.h>

// Problem constants (from reference)
#define N_NODES 50000
#define N_EDGES 150000
#define NODE_IN 64
#define EDGE_IN 16
#define DD 32          // node feature dim
#define EHID 128       // edge-network hidden
#define STEPS 3

// Device-verified harness dtypes: float inputs fp32, edge_index int32, output fp32.
__device__ __forceinline__ ushort f2b(float f) {
    __hip_bfloat16 b = __float2bfloat16(f);   // RNE
    return *reinterpret_cast<ushort*>(&b);
}

typedef __bf16 bf16x8 __attribute__((ext_vector_type(8)));
typedef float  f32x4  __attribute__((ext_vector_type(4)));

#define LDA  136   // As leading dim (ushorts): 272B rows, 16B-aligned, bank-skewed
#define HPAD 36    // Hs leading dim (floats): 144B rows

// ---------------------------------------------------------------------------
// prep: repack We2/We1 into MFMA-fragment-major bf16 buffers.
//  we2B unit u = ((bn*4+nt)*4+kt)*64 + lane, 8 ushorts:
//    bf16(We2[kt*32+(lane>>4)*8+j][bn*64+nt*16+(lane&15)])
//  we1B unit u = nt*64 + lane: bf16(We1[(lane>>4)*8+j][nt*16+(lane&15)]), k>=16 -> 0
__global__ __launch_bounds__(256) void prep(const float* __restrict__ we2,
                                            const float* __restrict__ we1,
                                            ushort* __restrict__ we2B,
                                            ushort* __restrict__ we1B) {
    int i = blockIdx.x * 256 + threadIdx.x;
    if (i < 16384) {
        int l = i & 63, f = i >> 6;           // f = bn*16 + nt*4 + kt
        int kt = f & 3, nt = (f >> 2) & 3, bn = f >> 4;
        int lr = l & 15, lg = l >> 4;
        int n = bn * 64 + nt * 16 + lr;
        int k0 = kt * 32 + lg * 8;
        ushort tmp[8];
#pragma unroll
        for (int j = 0; j < 8; ++j) tmp[j] = f2b(we2[(size_t)(k0 + j) * 1024 + n]);
        *(uint4*)(we2B + (size_t)i * 8) = *(uint4*)tmp;
    } else if (i < 16384 + 512) {
        int u = i - 16384;
        int l = u & 63, nt = u >> 6;
        int lr = l & 15, lg = l >> 4;
        int n = nt * 16 + lr;
        ushort tmp[8];
#pragma unroll
        for (int j = 0; j < 8; ++j) {
            int k = lg * 8 + j;
            tmp[j] = (k < EDGE_IN) ? f2b(we1[(size_t)k * EHID + n]) : (ushort)0;
        }
        *(uint4*)(we1B + (size_t)u * 8) = *(uint4*)tmp;
    }
}

// ---------------------------------------------------------------------------
// node_init: thread = node. Weight reads are wave-uniform -> LDS broadcast.
__global__ __launch_bounds__(256) void node_init(const float* __restrict__ x,
                                                 const float* __restrict__ Wn,
                                                 const float* __restrict__ bn,
                                                 float* __restrict__ h) {
    __shared__ float Wns[NODE_IN * DD];   // 8 KB
    __shared__ float bns[DD];
    int t = threadIdx.x;
    for (int i = t; i < NODE_IN * DD; i += 256) Wns[i] = Wn[i];
    if (t < DD) bns[t] = bn[t];
    __syncthreads();
    int n = blockIdx.x * 256 + t;
    if (n >= N_NODES) return;
    float xr[NODE_IN];
    const float4* xp = (const float4*)(x + (size_t)n * NODE_IN);
#pragma unroll
    for (int q = 0; q < NODE_IN / 4; ++q) *(float4*)&xr[q * 4] = xp[q];
    float out[DD];
#pragma unroll
    for (int o = 0; o < DD; ++o) {
        float s = bns[o];
#pragma unroll
        for (int i = 0; i < NODE_IN; ++i) s += xr[i] * Wns[i * DD + o];
        out[o] = fmaxf(s, 0.f);
    }
    float4* hp = (float4*)(h + (size_t)n * DD);
#pragma unroll
    for (int q = 0; q < DD / 4; ++q) hp[q] = *(float4*)&out[q * 4];
}

// ---------------------------------------------------------------------------
// fused_msg: block = 128 edges. B-fragments come straight from global L2
// (fragment-major we2B) -> main K-loop has ZERO barriers. 4 barriers total.
// Verified gfx950 16x16x32 mappings: A[m=lane&15][k=(lane>>4)*8+j],
// B[n=lane&15][k=(lane>>4)*8+j], D[row=(lane>>4)*4+reg][col=lane&15].
__global__ __launch_bounds__(256, 4) void fused_msg(const float* __restrict__ ea,
                                                    const ushort* __restrict__ we1B,
                                                    const float* __restrict__ be1,
                                                    const ushort* __restrict__ we2B,
                                                    const float* __restrict__ be2,
                                                    const int* __restrict__ ei,
                                                    const float* __restrict__ h,
                                                    float* __restrict__ agg) {
    __shared__ __attribute__((aligned(16))) ushort AsHs[128 * LDA];  // 34816 B
    __shared__ float b1s[EHID];                                      // 512 B
    __shared__ float be2s[DD * DD];                                  // 4096 B
    float* Hs = (float*)AsHs;       // [128][HPAD] fp32 view, reused after afrag hoist

    int t = threadIdx.x;
    if (t < EHID) b1s[t] = be1[t];
    for (int i = t; i < DD * DD; i += 256) be2s[i] = be2[i];

    int w = t >> 6, l = t & 63;
    int lr = l & 15, lg = l >> 4;

    // ---- Phase A input fragments straight from global ----
    bf16x8 afe[2];
#pragma unroll
    for (int mi = 0; mi < 2; ++mi) {
        int e = blockIdx.x * 128 + (w * 2 + mi) * 16 + lr;
        ushort tmp[8] = {0, 0, 0, 0, 0, 0, 0, 0};
        if (lg < 2 && e < N_EDGES) {
            const float4* p = (const float4*)(ea + (size_t)e * EDGE_IN + lg * 8);
            float4 a = p[0], b = p[1];
            tmp[0] = f2b(a.x); tmp[1] = f2b(a.y); tmp[2] = f2b(a.z); tmp[3] = f2b(a.w);
            tmp[4] = f2b(b.x); tmp[5] = f2b(b.y); tmp[6] = f2b(b.z); tmp[7] = f2b(b.w);
        }
        afe[mi] = *(bf16x8*)tmp;
    }
    __syncthreads();   // (1) b1s/be2s ready

    // ---- Phase A: g = relu(ea@We1+be1) via MFMA -> bf16 As[128][128] ----
#pragma unroll
    for (int nt = 0; nt < 8; ++nt) {
        bf16x8 bfe = *(const bf16x8*)(we1B + (size_t)((nt << 6) + l) * 8);
        int kh = nt * 16 + lr;
        float bb = b1s[kh];
#pragma unroll
        for (int mi = 0; mi < 2; ++mi) {
            f32x4 acc = (f32x4){0.f, 0.f, 0.f, 0.f};
            acc = __builtin_amdgcn_mfma_f32_16x16x32_bf16(afe[mi], bfe, acc, 0, 0, 0);
#pragma unroll
            for (int r = 0; r < 4; ++r)
                AsHs[((w * 2 + mi) * 16 + lg * 4 + r) * LDA + kh] = f2b(fmaxf(acc[r] + bb, 0.f));
        }
    }
    __syncthreads();   // (2) As complete

    bf16x8 afrag[2][4];
#pragma unroll
    for (int mi = 0; mi < 2; ++mi)
#pragma unroll
        for (int kt = 0; kt < 4; ++kt)
            afrag[mi][kt] = *(const bf16x8*)(&AsHs[((w * 2 + mi) * 16 + lr) * LDA + kt * 32 + lg * 8]);
    __syncthreads();   // (3) As reads done -> reuse as Hs

    // ---- Gather h[src] rows into Hs ----
    {
        int le = t >> 1, half = t & 1;
        int e = blockIdx.x * 128 + le;
        float4* hd = (float4*)(Hs + le * HPAD + half * 16);
        if (e < N_EDGES) {
            int src = ei[e];
            const float4* hr = (const float4*)(h + (size_t)src * DD + half * 16);
            hd[0] = hr[0]; hd[1] = hr[1]; hd[2] = hr[2]; hd[3] = hr[3];
        } else {
            float4 z = make_float4(0.f, 0.f, 0.f, 0.f);
            hd[0] = z; hd[1] = z; hd[2] = z; hd[3] = z;
        }
    }
    __syncthreads();   // (4) Hs ready — last barrier in the kernel

    float m_acc[2][4][2];
#pragma unroll
    for (int mi = 0; mi < 2; ++mi)
#pragma unroll
        for (int r = 0; r < 4; ++r) { m_acc[mi][r][0] = 0.f; m_acc[mi][r][1] = 0.f; }

    // ---- Main loop: 16 column tiles, B-frags direct from L2, no barriers ----
    for (int bn = 0; bn < 16; ++bn) {
        f32x4 acc[2][4];
#pragma unroll
        for (int mi = 0; mi < 2; ++mi)
#pragma unroll
            for (int nt = 0; nt < 4; ++nt) acc[mi][nt] = (f32x4){0.f, 0.f, 0.f, 0.f};

#pragma unroll
        for (int kt = 0; kt < 4; ++kt) {
            const ushort* base = we2B + (size_t)((bn * 16 + kt) * 64 + l) * 8;
            bf16x8 b0 = *(const bf16x8*)(base);            // nt=0: f = bn*16+0*4+kt
            bf16x8 b1 = *(const bf16x8*)(base + 2048);     // nt=1 (+4*64*8 ushorts)
            bf16x8 b2 = *(const bf16x8*)(base + 4096);     // nt=2
            bf16x8 b3 = *(const bf16x8*)(base + 6144);     // nt=3
            acc[0][0] = __builtin_amdgcn_mfma_f32_16x16x32_bf16(afrag[0][kt], b0, acc[0][0], 0, 0, 0);
            acc[1][0] = __builtin_amdgcn_mfma_f32_16x16x32_bf16(afrag[1][kt], b0, acc[1][0], 0, 0, 0);
            acc[0][1] = __builtin_amdgcn_mfma_f32_16x16x32_bf16(afrag[0][kt], b1, acc[0][1], 0, 0, 0);
            acc[1][1] = __builtin_amdgcn_mfma_f32_16x16x32_bf16(afrag[1][kt], b1, acc[1][1], 0, 0, 0);
            acc[0][2] = __builtin_amdgcn_mfma_f32_16x16x32_bf16(afrag[0][kt], b2, acc[0][2], 0, 0, 0);
            acc[1][2] = __builtin_amdgcn_mfma_f32_16x16x32_bf16(afrag[1][kt], b2, acc[1][2], 0, 0, 0);
            acc[0][3] = __builtin_amdgcn_mfma_f32_16x16x32_bf16(afrag[0][kt], b3, acc[0][3], 0, 0, 0);
            acc[1][3] = __builtin_amdgcn_mfma_f32_16x16x32_bf16(afrag[1][kt], b3, acc[1][3], 0, 0, 0);
        }

        // Fold Wm tile into message accumulators: col -> i=2bn+(nt>>1), o=16*(nt&1)+lr
#pragma unroll
        for (int mi = 0; mi < 2; ++mi) {
#pragma unroll
            for (int r = 0; r < 4; ++r) {
                int row = (w * 2 + mi) * 16 + lg * 4 + r;
                float2 hv = *(const float2*)(Hs + row * HPAD + bn * 2);
#pragma unroll
                for (int nt = 0; nt < 4; ++nt) {
                    float hi = (nt >> 1) ? hv.y : hv.x;
                    m_acc[mi][r][nt & 1] += hi * (acc[mi][nt][r] + be2s[bn * 64 + nt * 16 + lr]);
                }
            }
        }
    }

    // ---- Scatter: agg[dst] += m ----
#pragma unroll
    for (int mi = 0; mi < 2; ++mi) {
#pragma unroll
        for (int r = 0; r < 4; ++r) {
            int le = (w * 2 + mi) * 16 + lg * 4 + r;
            int e = blockIdx.x * 128 + le;
            if (e < N_EDGES) {
                int dst = ei[N_EDGES + e];
                float* ar = agg + (size_t)dst * DD;
                atomicAdd(ar + lr,      m_acc[mi][r][0]);
                atomicAdd(ar + lr + 16, m_acc[mi][r][1]);
            }
        }
    }
}

// ---------------------------------------------------------------------------
// conv + GRU: thread = node. All weight reads wave-uniform (LDS broadcast).
// Also zeroes agg for the next step (saves per-step memsets).
__global__ __launch_bounds__(256) void conv_gru(float* __restrict__ agg,
                                                float* __restrict__ h,
                                                const float* __restrict__ Wroot,
                                                const float* __restrict__ bconv,
                                                const float* __restrict__ Wih,
                                                const float* __restrict__ Whh,
                                                const float* __restrict__ bih,
                                                const float* __restrict__ bhh,
                                                float* __restrict__ out) {
    __shared__ float Wr[DD * DD];        // 4 KB
    __shared__ float Wi[3 * DD * DD];    // 12 KB
    __shared__ float Wh[3 * DD * DD];    // 12 KB
    __shared__ float bc[DD], bi[3 * DD], bh[3 * DD];
    int t = threadIdx.x;
    for (int i = t; i < DD * DD; i += 256) Wr[i] = Wroot[i];
    for (int i = t; i < 3 * DD * DD; i += 256) { Wi[i] = Wih[i]; Wh[i] = Whh[i]; }
    if (t < DD) bc[t] = bconv[t];
    if (t < 3 * DD) { bi[t] = bih[t]; bh[t] = bhh[t]; }
    __syncthreads();

    int n = blockIdx.x * 256 + t;
    if (n >= N_NODES) return;

    float hr[DD], ag[DD];
    float4* hp = (float4*)(h + (size_t)n * DD);
    float4* ap = (float4*)(agg + (size_t)n * DD);
#pragma unroll
    for (int q = 0; q < DD / 4; ++q) { *(float4*)&hr[q * 4] = hp[q]; *(float4*)&ag[q * 4] = ap[q]; }
    float4 z4 = make_float4(0.f, 0.f, 0.f, 0.f);
#pragma unroll
    for (int q = 0; q < DD / 4; ++q) ap[q] = z4;   // agg := 0 for next step

    // conv = relu(agg + h @ Wroot + bconv)
    float cv[DD];
#pragma unroll
    for (int o = 0; o < DD; ++o) {
        float s = bc[o] + ag[o];
#pragma unroll
        for (int i = 0; i < DD; ++i) s += hr[i] * Wr[i * DD + o];
        cv[o] = fmaxf(s, 0.f);
    }

    // GRU (gate order r, z, n), 4 outputs per chunk
    float4* op = out ? (float4*)(out + (size_t)n * DD) : nullptr;
    for (int oc = 0; oc < DD / 4; ++oc) {
        float res[4];
#pragma unroll
        for (int j = 0; j < 4; ++j) {
            int o = oc * 4 + j;
            float gir = bi[o], giz = bi[DD + o], gin = bi[2 * DD + o];
            float ghr = bh[o], ghz = bh[DD + o], ghn = bh[2 * DD + o];
#pragma unroll
            for (int i = 0; i < DD; ++i) {
                gir += cv[i] * Wi[o * DD + i];
                giz += cv[i] * Wi[(DD + o) * DD + i];
                gin += cv[i] * Wi[(2 * DD + o) * DD + i];
                ghr += hr[i] * Wh[o * DD + i];
                ghz += hr[i] * Wh[(DD + o) * DD + i];
                ghn += hr[i] * Wh[(2 * DD + o) * DD + i];
            }
            float r = 1.f / (1.f + expf(-(gir + ghr)));
            float z = 1.f / (1.f + expf(-(giz + ghz)));
            float nn = tanhf(gin + r * ghn);
            float hv = hp[oc].x;   // placeholder, replaced below per j
            hv = ((const float*)&hp[oc])[j];   // chunk reload: old h (not yet overwritten)
            res[j] = (1.f - z) * nn + z * hv;
        }
        float4 r4 = make_float4(res[0], res[1], res[2], res[3]);
        hp[oc] = r4;
        if (op) op[oc] = r4;
    }
}

// ---------------------------------------------------------------------------
extern "C" void kernel_launch(void* const* d_in, const int* in_sizes, int n_in,
                              void* d_out, int out_size, void* d_ws, size_t ws_size,
                              hipStream_t stream) {
    const float* x    = (const float*)d_in[0];
    const int*   ei   = (const int*)d_in[1];
    const float* ea   = (const float*)d_in[2];
    const float* Wn   = (const float*)d_in[3];
    const float* bn   = (const float*)d_in[4];
    const float* We1  = (const float*)d_in[5];
    const float* be1  = (const float*)d_in[6];
    const float* We2  = (const float*)d_in[7];
    const float* be2  = (const float*)d_in[8];
    const float* Wroot= (const float*)d_in[9];
    const float* bconv= (const float*)d_in[10];
    const float* Wih  = (const float*)d_in[11];
    const float* Whh  = (const float*)d_in[12];
    const float* bih  = (const float*)d_in[13];
    const float* bhh  = (const float*)d_in[14];
    float* out = (float*)d_out;   // fp32 output (device-verified)

    // ---- Workspace: 13.07 MB (proven-safe footprint) ----
    char* ws = (char*)d_ws;
    float*  h    = (float*)(ws);                    // 6.4 MB
    float*  agg  = (float*)(ws + 6400000);          // 6.4 MB
    ushort* we2B = (ushort*)(ws + 12800000);        // 256 KB fragment-major We2T
    ushort* we1B = (ushort*)(ws + 13062144);        // 8 KB   fragment-major We1T

    prep<<<66, 256, 0, stream>>>(We2, We1, we2B, we1B);
    node_init<<<(N_NODES + 255) / 256, 256, 0, stream>>>(x, Wn, bn, h);
    hipMemsetAsync(agg, 0, (size_t)N_NODES * DD * sizeof(float), stream);

    for (int step = 0; step < STEPS; ++step) {
        fused_msg<<<(N_EDGES + 127) / 128, 256, 0, stream>>>(ea, we1B, be1, we2B, be2,
                                                             ei, h, agg);
        conv_gru<<<(N_NODES + 255) / 256, 256, 0, stream>>>(agg, h, Wroot, bconv,
                                                            Wih, Whh, bih, bhh,
                                                            (step == STEPS - 1) ? out : nullptr);
    }
}